// Round 1
// baseline (2125.474 us; speedup 1.0000x reference)
//
#include <hip/hip_runtime.h>
#include <hip/hip_bf16.h>

// SignalDecoder: 2-layer bidirectional LSTM, 52 steps, B=1024, HID=256.
// Round 4: PERSISTENT kernel. R3 lesson: 104 launches x ~14.8us; per-stage cost is
// launch gap + re-streaming 96KB weights/block/stage + C round-trip, not math
// (3.22 GFLOP/stage = ~1.3us at peak). New: one kernel, 256 blocks x 512 thr
// (1 block/CU), weights resident for the whole run:
//   - layer-0 slice (cell p, hsl): 96 KB in LDS, DMA'd once.
//   - layer-1 slice (cell 2+p, hsl): in REGISTERS (wave w = (mh,g): gate g's 24
//     kc-frags = 96 VGPR), epilogue gathers the 4 gates via a small LDS exchange.
//   - C-state in registers for all 52 steps (fixed owner per (row,cell,hid)).
// Rows are independent => blocks sharing a 128-row tile (mb = bid&7) form a
// 32-block cluster; barriers are per-cluster (atomic ctr + __threadfence, agent
// scope). mb = bid&7 also aligns clusters with XCDs under %8 dispatch (perf only).
// Stage-1 A (128rows x 768) staged per 32-row quarter into LDS via global_load_lds
// with XOR-swizzle (rule #21: linear dest, inv-swizzled source, swizzled ds_read).

#define NSTEPS 52

typedef __attribute__((ext_vector_type(8))) short bf16x8;
typedef __attribute__((ext_vector_type(4))) float f32x4;
typedef __attribute__((ext_vector_type(4))) unsigned int u32x4;

__device__ __forceinline__ unsigned short f2bf(float f) {
  union { float f; unsigned int u; } v; v.f = f;
  unsigned int r = v.u + 0x7fffu + ((v.u >> 16) & 1u);  // RNE
  return (unsigned short)(r >> 16);
}

__device__ __forceinline__ float sigm(float x) { return 1.f / (1.f + __expf(-x)); }
__device__ __forceinline__ float tanh_f(float x) { return 2.f / (1.f + __expf(-2.f * x)) - 1.f; }

__device__ __forceinline__ void async_ld16(const unsigned short* g, unsigned short* l) {
  __builtin_amdgcn_global_load_lds(
      (const __attribute__((address_space(1))) unsigned int*)g,
      (__attribute__((address_space(3))) unsigned int*)l, 16, 0, 0);
}

// Pack weights: cell c (0=l0f,1=l0b,2=l1f,3=l1b), Wcat = [W_ih (K=512) | W_hh (K=256)],
// chunk (c, n16, kc): lane l holds W[n16*16 + (l&15)][kc*32 + (l>>4)*8 + j], j=0..7.
// chunk short-offset = ((c*64 + n16)*24 + kc)*512 + lane*8. n16 = gate*16 + hsl.
// bsum[c*1024+n] = b_ih+b_hh.
__global__ void wpack_kernel(const float* __restrict__ Wih0, const float* __restrict__ Whh0,
                             const float* __restrict__ bih0, const float* __restrict__ bhh0,
                             const float* __restrict__ Wih1, const float* __restrict__ Whh1,
                             const float* __restrict__ bih1, const float* __restrict__ bhh1,
                             unsigned short* __restrict__ wpack, float* __restrict__ bsum) {
  int tid = blockIdx.x * 256 + threadIdx.x;  // 4*64*24*64 = 393216 threads
  int lane = tid & 63;
  int chunk = tid >> 6;
  int kc = chunk % 24;
  int cn = chunk / 24;
  int n16 = cn & 63;
  int c = cn >> 6;
  int n = n16 * 16 + (lane & 15);
  int k0 = kc * 32 + (lane >> 4) * 8;
  const float* Wih = (c < 2) ? Wih0 : Wih1;
  const float* Whh = (c < 2) ? Whh0 : Whh1;
  int d = c & 1;
  unsigned short tmp[8];
#pragma unroll
  for (int j = 0; j < 8; j++) {
    int k = k0 + j;
    float val = (k < 512) ? Wih[(d * 1024 + n) * 512 + k]
                          : Whh[(d * 1024 + n) * 256 + (k - 512)];
    tmp[j] = f2bf(val);
  }
  *(u32x4*)(wpack + (size_t)tid * 8) = *(const u32x4*)tmp;
  if (tid < 4096) {
    int c2 = tid >> 10, n2 = tid & 1023;
    float b = (c2 < 2) ? (bih0[(c2 & 1) * 1024 + n2] + bhh0[(c2 & 1) * 1024 + n2])
                       : (bih1[(c2 & 1) * 1024 + n2] + bhh1[(c2 & 1) * 1024 + n2]);
    bsum[tid] = b;
  }
}

// init: h0 -> H slot 1 ([row][cell*256+hid] bf16), c0 -> C ([row][cell*256+hid] fp32)
// Also zero the 256 barrier counters (re-zeroed every launch / graph replay).
__global__ void init_kernel(const float* __restrict__ code,
                            unsigned short* __restrict__ H1, float* __restrict__ C,
                            unsigned int* __restrict__ ctrs) {
  int t = blockIdx.x * 256 + threadIdx.x;  // 1M threads
  int row = t >> 10, col = t & 1023;
  H1[t] = f2bf(code[row * 2048 + col]);
  C[t] = code[row * 2048 + 1024 + col];
  if (blockIdx.x == 0 && threadIdx.x < 256) ctrs[threadIdx.x] = 0;
}

// 32-block cluster barrier: release stores -> arrive -> spin -> acquire.
// Counter is monotonic (expect = 32*bar), so no reset race across barriers.
__device__ __forceinline__ void cl_barrier(unsigned int* c, unsigned int expect) {
  __syncthreads();  // all waves' stores issued & vmcnt-drained
  if (threadIdx.x == 0) {
    __threadfence();  // agent release: flush h-writes toward L3
    __hip_atomic_fetch_add(c, 1u, __ATOMIC_RELAXED, __HIP_MEMORY_SCOPE_AGENT);
    while (__hip_atomic_load(c, __ATOMIC_RELAXED, __HIP_MEMORY_SCOPE_AGENT) < expect)
      __builtin_amdgcn_s_sleep(1);
    __threadfence();  // agent acquire: invalidate L1/L2 before re-reading H
  }
  __syncthreads();
}

// Persistent LSTM: block bx -> mb = bx&7 (cluster / 128-row tile), hsl = (bx>>3)&15,
// p = bx>>7. Owns cells {p (layer0), 2+p (layer1)} x hid slice [hsl*16,+16) x rows
// [mb*128,+128). 8 waves: stage-0 row-split (w*16 rows), stage-1 (mh=w>>2, g1=w&3).
__global__ __launch_bounds__(512, 2) void lstm_persistent(
    const unsigned short* __restrict__ wpack, const float* __restrict__ bsum,
    const float* __restrict__ Cg, unsigned short* __restrict__ H0,
    unsigned short* __restrict__ H1, float* __restrict__ out,
    unsigned int* __restrict__ ctrs) {
  __shared__ unsigned short W0[96 * 512];   // 96 KB: layer-0 weights, resident
  __shared__ unsigned short A1[32 * 768];   // 48 KB: stage-1 A quarter (swizzled)
  __shared__ float EX[32 * 65];             // 8.3 KB: stage-1 gate exchange (+1 pad)

  const int bx = blockIdx.x;
  const int mb = bx & 7;
  const int hsl = (bx >> 3) & 15;
  const int p = bx >> 7;
  const int tid = threadIdx.x;
  const int lane = tid & 63;
  const int w = tid >> 6;
  const int q = lane >> 4;
  const int ln = lane & 15;
  const int g1 = w & 3;   // stage-1 wave gate
  const int mh = w >> 2;  // stage-1 wave m-half (16 rows within 32-row quarter)

  // --- layer-1 weights -> registers (gate g1's 24 kc-frags, 96 VGPR)
  bf16x8 wb1[24];
#pragma unroll
  for (int kc = 0; kc < 24; kc++)
    wb1[kc] = *(const bf16x8*)(
        wpack + (size_t)((((2 + p) * 64 + g1 * 16 + hsl) * 24 + kc)) * 512 + lane * 8);

  // --- layer-0 weights -> LDS (once), 96 chunks of 1KB via DMA
#pragma unroll
  for (int i = 0; i < 12; i++) {
    int ci = w + i * 8;
    int gate = ci & 3, kc = ci >> 2;
    async_ld16(wpack + (size_t)(((p * 64 + gate * 16 + hsl) * 24 + kc)) * 512 + lane * 8,
               W0 + (size_t)ci * 512);
  }

  // --- biases and register-resident C-state
  const int colh = hsl * 16 + ln;  // stage-0 lane column
  float brg0[4];
#pragma unroll
  for (int g = 0; g < 4; g++) brg0[g] = bsum[p * 1024 + g * 256 + colh];

  const int ehid = tid & 15;        // stage-1 epilogue thread column-in-slice
  const int erow = tid >> 4;        // 0..31 row within quarter
  const int colh1 = hsl * 16 + ehid;
  float brg1[4];
#pragma unroll
  for (int g = 0; g < 4; g++) brg1[g] = bsum[(2 + p) * 1024 + g * 256 + colh1];

  float c0r[4];  // layer-0 C: rows mb*128 + w*16 + q*4 + r, col p*256+colh
#pragma unroll
  for (int r = 0; r < 4; r++)
    c0r[r] = Cg[(size_t)(mb * 128 + w * 16 + q * 4 + r) * 1024 + p * 256 + colh];
  float c1r[4];  // layer-1 C: per quarter qq: row mb*128 + qq*32 + erow
#pragma unroll
  for (int qq = 0; qq < 4; qq++)
    c1r[qq] = Cg[(size_t)(mb * 128 + qq * 32 + erow) * 1024 + (2 + p) * 256 + colh1];

  unsigned int* ctr = ctrs + mb * 32;  // one 128B line per cluster
  unsigned int bar = 0;

  __syncthreads();  // W0 DMA complete

  for (int t = 0; t < NSTEPS; t++) {
    const unsigned short* __restrict__ Hprev = (t & 1) ? H0 : H1;
    unsigned short* __restrict__ Hcur = (t & 1) ? H1 : H0;

    // ================= stage 0: layer 0, cell p (same math as verified R3) ====
    f32x4 acc[4];
#pragma unroll
    for (int g = 0; g < 4; g++) acc[g] = (f32x4){0.f, 0.f, 0.f, 0.f};

    const int arow = (mb * 128 + w * 16 + ln) * 1024 + q * 8;
    auto s0chunk = [&](const unsigned short* base, int kcb) {
      bf16x8 afr[8];
#pragma unroll
      for (int kk = 0; kk < 8; kk++) afr[kk] = *(const bf16x8*)(base + kk * 32);
#pragma unroll
      for (int kk = 0; kk < 8; kk++) {
#pragma unroll
        for (int g = 0; g < 4; g++) {
          bf16x8 bf = *(const bf16x8*)(W0 + (size_t)((kcb + kk) * 4 + g) * 512 + lane * 8);
          acc[g] = __builtin_amdgcn_mfma_f32_16x16x32_bf16(afr[kk], bf, acc[g], 0, 0, 0);
        }
      }
    };
    if (t > 0) {  // t==0: x-part (y_prev) is zero -> skip kc 0..15
      s0chunk(Hprev + arow + 512, 0);        // x cols 0..255   (cells 2,3)
      s0chunk(Hprev + arow + 512 + 256, 8);  // x cols 256..511
    }
    s0chunk(Hprev + arow + p * 256, 16);     // h-part: own cell p

#pragma unroll
    for (int r = 0; r < 4; r++) {
      float iv = sigm(acc[0][r] + brg0[0]);
      float fv = sigm(acc[1][r] + brg0[1]);
      float gv = tanh_f(acc[2][r] + brg0[2]);
      float ov = sigm(acc[3][r] + brg0[3]);
      float c2 = fv * c0r[r] + iv * gv;
      c0r[r] = c2;
      float hv = ov * tanh_f(c2);
      Hcur[(size_t)(mb * 128 + w * 16 + q * 4 + r) * 1024 + p * 256 + colh] = f2bf(hv);
    }

    bar++;
    cl_barrier(ctr, 32 * bar);  // h0 visible to the cluster

    // ================= stage 1: layer 1, cell 2+p, 4x 32-row quarters =========
#pragma unroll
    for (int qq = 0; qq < 4; qq++) {
      // DMA 32 rows x 768 cols into A1 (3072 x 16B units, 6 rounds).
      // Storage swizzle: unit(row,k16) = row*96 + (k16 ^ (row&7)); DMA dest is
      // linear in u, so source fetches logical k16 = (u%96) ^ (row&7).
#pragma unroll
      for (int rd = 0; rd < 6; rd++) {
        int u = rd * 512 + tid;
        int lrow = u / 96;
        int k16 = (u % 96) ^ (lrow & 7);
        int k0 = k16 * 8;
        int grow = mb * 128 + qq * 32 + lrow;
        const unsigned short* src =
            (k0 < 512) ? (Hcur + (size_t)grow * 1024 + k0)                       // x1 = h0
                       : (Hprev + (size_t)grow * 1024 + 512 + p * 256 + (k0 - 512));  // own h1
        async_ld16(src, A1 + (size_t)u * 8);
      }
      __syncthreads();  // DMA drained; also fences prev quarter's EX reads

      // MFMA: wave (mh,g1): 16 rows x 16 cols (gate g1), K=768, B from registers
      f32x4 a1acc = (f32x4){0.f, 0.f, 0.f, 0.f};
      const int lrow = mh * 16 + ln;
#pragma unroll
      for (int kc = 0; kc < 24; kc++) {
        int k16 = ((kc * 4 + q) ^ (lrow & 7));
        bf16x8 af = *(const bf16x8*)(A1 + (size_t)(lrow * 96 + k16) * 8);
        a1acc = __builtin_amdgcn_mfma_f32_16x16x32_bf16(af, wb1[kc], a1acc, 0, 0, 0);
      }

      // gate exchange: [row32][4 gates x 16 hid], +1 pad against bank conflicts
#pragma unroll
      for (int r = 0; r < 4; r++)
        EX[(mh * 16 + q * 4 + r) * 65 + g1 * 16 + ln] = a1acc[r];
      __syncthreads();

      // epilogue: thread (erow, ehid) gathers its 4 gates
      float gvs[4];
#pragma unroll
      for (int g = 0; g < 4; g++) gvs[g] = EX[erow * 65 + g * 16 + ehid] + brg1[g];
      float iv = sigm(gvs[0]);
      float fv = sigm(gvs[1]);
      float gg = tanh_f(gvs[2]);
      float ov = sigm(gvs[3]);
      float c2 = fv * c1r[qq] + iv * gg;
      c1r[qq] = c2;
      float hv = ov * tanh_f(c2);
      int grow = mb * 128 + qq * 32 + erow;
      Hcur[(size_t)grow * 1024 + (2 + p) * 256 + colh1] = f2bf(hv);
      out[(size_t)grow * (NSTEPS * 512) + t * 512 + p * 256 + colh1] = hv;
    }

    if (t + 1 < NSTEPS) {
      bar++;
      cl_barrier(ctr, 32 * bar);  // h1 visible before next step's stage 0
    }
  }
}

extern "C" void kernel_launch(void* const* d_in, const int* in_sizes, int n_in,
                              void* d_out, int out_size, void* d_ws, size_t ws_size,
                              hipStream_t stream) {
  const float* code = (const float*)d_in[0];
  // d_in[1] = x  -- unused by the reference
  const float* Wih0 = (const float*)d_in[2];
  const float* Whh0 = (const float*)d_in[3];
  const float* bih0 = (const float*)d_in[4];
  const float* bhh0 = (const float*)d_in[5];
  const float* Wih1 = (const float*)d_in[6];
  const float* Whh1 = (const float*)d_in[7];
  const float* bih1 = (const float*)d_in[8];
  const float* bhh1 = (const float*)d_in[9];

  // d_ws layout (unchanged from R3 + 1KB barrier counters at tail)
  unsigned short* wpack = (unsigned short*)d_ws;                        // 6,291,456 B
  float* bsum = (float*)((char*)d_ws + 6291456);                        // 16 KB
  float* C    = (float*)((char*)d_ws + 6291456 + 16384);                // 4 MB
  unsigned short* H0 = (unsigned short*)((char*)d_ws + 6291456 + 16384 + 4194304);  // 2 MB
  unsigned short* H1 = H0 + 1024 * 1024;                                // 2 MB
  unsigned int* ctrs = (unsigned int*)((char*)d_ws + 14696448);         // 1 KB

  float* out = (float*)d_out;

  wpack_kernel<<<1536, 256, 0, stream>>>(Wih0, Whh0, bih0, bhh0,
                                         Wih1, Whh1, bih1, bhh1, wpack, bsum);
  init_kernel<<<4096, 256, 0, stream>>>(code, H1, C, ctrs);
  lstm_persistent<<<256, 512, 0, stream>>>(wpack, bsum, C, H0, H1, out, ctrs);
}

// Round 2
// 1472.930 us; speedup vs baseline: 1.4430x; 1.4430x over previous
//
#include <hip/hip_runtime.h>
#include <hip/hip_bf16.h>

// SignalDecoder: 2-layer bidirectional LSTM, 52 steps, B=1024, HID=256.
// Round 5: back to 104 launches (R3 structure, verified math), now with a
// pipelined weight stream. R4 post-mortem: persistent kernel's agent-scope
// fences invalidate L2 104x -> 32x-duplicated A-reads stream from L3 with
// ~900cy latency on a serialized chain => 38.8us/step (WORSE than launches).
// Launch boundary = free fence, L2 stays warm (mb=bx&7 pins a cluster's
// H/C rows to one XCD's L2 under the %8 dispatch heuristic - perf only).
// R3's remaining cost was the weight DMA (96KB/block from L3) fully drained
// by one __syncthreads before any MFMA. Now: 6 groups x 16KB, triple-buffered
// LDS (48KB), counted s_waitcnt vmcnt(N) + raw s_barrier (T3/T4: never drain
// to 0 mid-loop), MFMA on group g overlaps DMA of g+1,g+2; A/C/bias
// prefetched to regs at the top. FP order identical to R3 => same absmax.

#define NSTEPS 52

typedef __attribute__((ext_vector_type(8))) short bf16x8;
typedef __attribute__((ext_vector_type(4))) float f32x4;
typedef __attribute__((ext_vector_type(4))) unsigned int u32x4;

template <int I> struct IC { static constexpr int v = I; };

__device__ __forceinline__ unsigned short f2bf(float f) {
  union { float f; unsigned int u; } v; v.f = f;
  unsigned int r = v.u + 0x7fffu + ((v.u >> 16) & 1u);  // RNE
  return (unsigned short)(r >> 16);
}

__device__ __forceinline__ float sigm(float x) { return 1.f / (1.f + __expf(-x)); }
__device__ __forceinline__ float tanh_f(float x) { return 2.f / (1.f + __expf(-2.f * x)) - 1.f; }

__device__ __forceinline__ void async_ld16(const unsigned short* g, unsigned short* l) {
  __builtin_amdgcn_global_load_lds(
      (const __attribute__((address_space(1))) unsigned int*)g,
      (__attribute__((address_space(3))) unsigned int*)l, 16, 0, 0);
}

// Pack weights: cell c (0=l0f,1=l0b,2=l1f,3=l1b), Wcat = [W_ih (K=512) | W_hh (K=256)],
// chunk (c, n16, kc): lane l holds W[n16*16 + (l&15)][kc*32 + (l>>4)*8 + j], j=0..7.
// chunk short-offset = ((c*64 + n16)*24 + kc)*512 + lane*8. n16 = gate*16 + hsl.
// bsum[c*1024+n] = b_ih+b_hh.
__global__ void wpack_kernel(const float* __restrict__ Wih0, const float* __restrict__ Whh0,
                             const float* __restrict__ bih0, const float* __restrict__ bhh0,
                             const float* __restrict__ Wih1, const float* __restrict__ Whh1,
                             const float* __restrict__ bih1, const float* __restrict__ bhh1,
                             unsigned short* __restrict__ wpack, float* __restrict__ bsum) {
  int tid = blockIdx.x * 256 + threadIdx.x;  // 4*64*24*64 = 393216 threads
  int lane = tid & 63;
  int chunk = tid >> 6;
  int kc = chunk % 24;
  int cn = chunk / 24;
  int n16 = cn & 63;
  int c = cn >> 6;
  int n = n16 * 16 + (lane & 15);
  int k0 = kc * 32 + (lane >> 4) * 8;
  const float* Wih = (c < 2) ? Wih0 : Wih1;
  const float* Whh = (c < 2) ? Whh0 : Whh1;
  int d = c & 1;
  unsigned short tmp[8];
#pragma unroll
  for (int j = 0; j < 8; j++) {
    int k = k0 + j;
    float val = (k < 512) ? Wih[(d * 1024 + n) * 512 + k]
                          : Whh[(d * 1024 + n) * 256 + (k - 512)];
    tmp[j] = f2bf(val);
  }
  *(u32x4*)(wpack + (size_t)tid * 8) = *(const u32x4*)tmp;
  if (tid < 4096) {
    int c2 = tid >> 10, n2 = tid & 1023;
    float b = (c2 < 2) ? (bih0[(c2 & 1) * 1024 + n2] + bhh0[(c2 & 1) * 1024 + n2])
                       : (bih1[(c2 & 1) * 1024 + n2] + bhh1[(c2 & 1) * 1024 + n2]);
    bsum[tid] = b;
  }
}

// init: h0 -> H slot 1 ([row][cell*256+hid] bf16), c0 -> C ([row][cell*256+hid] fp32)
__global__ void init_kernel(const float* __restrict__ code,
                            unsigned short* __restrict__ H1, float* __restrict__ C) {
  int t = blockIdx.x * 256 + threadIdx.x;  // 1M threads
  int row = t >> 10, col = t & 1023;
  H1[t] = f2bf(code[row * 2048 + col]);
  C[t] = code[row * 2048 + 1024 + col];
}

// One LSTM stage: gates = A[1024 x 768] * Wcat^T for 2 cells, fused LSTM epilogue.
// Block = (cell01, hsl in 0..15 -> 16 hidden, mb in 0..7 -> 128 rows). 512 threads.
// A(row,k): k<512 -> Xb[row*1024+k]; k>=512 -> Hp[row*1024 + cell*256 + k-512].
// Weight stream: group g covers kc = 4g..4g+3 (16 chunks x 1KB = 16KB); 3 LDS
// buffers; wave w DMA-loads chunks 2w, 2w+1 of each group.
template <int KC0>
__device__ __forceinline__ void stage_body(
    const unsigned short* __restrict__ Xb, const unsigned short* __restrict__ Hp,
    unsigned short* __restrict__ Hw, float* __restrict__ C,
    const float* __restrict__ bsum, const unsigned short* __restrict__ wpack,
    float* __restrict__ out, int cell0, int step,
    unsigned short* Blds) {
  const int bx = blockIdx.x;
  const int mb = bx & 7;
  const int hsl = (bx >> 3) & 15;
  const int cell = cell0 + (bx >> 7);
  const int tid = threadIdx.x;
  const int lane = tid & 63;
  const int w = tid >> 6;          // wave id = M-tile within the 128-row block
  const int q = lane >> 4;
  const int ln = lane & 15;

  constexpr int G0 = KC0 / 4;      // first kc-group
  constexpr int NG = 6 - G0;       // number of groups (6 normal, 2 at t==0 stage0)

  // --- early prefetch to registers: bias, C-state, A-fragments (L2-warm).
  const int colh = hsl * 16 + ln;
  float brg[4];
#pragma unroll
  for (int g = 0; g < 4; g++) brg[g] = bsum[cell * 1024 + g * 256 + colh];
  float cp[4];
#pragma unroll
  for (int r = 0; r < 4; r++)
    cp[r] = C[(size_t)(mb * 128 + w * 16 + q * 4 + r) * 1024 + cell * 256 + colh];

  const int arow = (mb * 128 + w * 16 + ln) * 1024 + q * 8;
  bf16x8 afr[24];
#pragma unroll
  for (int kc = KC0; kc < 24; kc++) {
    const unsigned short* ap = (kc < 16) ? (Xb + arow + kc * 32)
                                         : (Hp + arow + cell * 256 + (kc - 16) * 32);
    afr[kc] = *(const bf16x8*)ap;
  }

  // --- weight group DMA issue (wave w -> chunks 2w, 2w+1; chunk ci = kcl*4+gate)
  auto issueG = [&](int g) {
#pragma unroll
    for (int j = 0; j < 2; j++) {
      int ci = w * 2 + j;
      int kcl = ci >> 2, gate = ci & 3;
      async_ld16(
          wpack + ((size_t)((cell * 64 + gate * 16 + hsl) * 24 + g * 4 + kcl)) * 512 + lane * 8,
          Blds + (size_t)((g % 3) * 16 + ci) * 512);
    }
  };
  issueG(G0);
  if (NG > 1) issueG(G0 + 1);
  if (NG > 2) issueG(G0 + 2);

  f32x4 acc[4];
#pragma unroll
  for (int g = 0; g < 4; g++) acc[g] = (f32x4){0.f, 0.f, 0.f, 0.f};

  // --- pipelined consume: wait own vmcnt down to (W-ops younger than group g),
  // raw barrier, 16 MFMA, then (if buffer will be reused) lgkm-drain + barrier +
  // issue group g+3. N is safe: issueG builtins keep program order among
  // themselves; stray prefetch loads only make the wait conservative.
  auto group = [&](auto GI) {
    constexpr int gi = GI.v;
    constexpr int g = G0 + gi;
    constexpr int rem = NG - 1 - gi;           // groups issued after g
    constexpr int N = 2 * (rem < 2 ? rem : 2); // their op count (2 per group)
    asm volatile("s_waitcnt vmcnt(%0)" ::"n"(N) : "memory");
    __builtin_amdgcn_s_barrier();
    const unsigned short* buf = Blds + (size_t)(g % 3) * 8192;
    __builtin_amdgcn_s_setprio(1);
#pragma unroll
    for (int kcl = 0; kcl < 4; kcl++) {
#pragma unroll
      for (int gt = 0; gt < 4; gt++) {
        bf16x8 bf = *(const bf16x8*)(buf + (size_t)(kcl * 4 + gt) * 512 + lane * 8);
        acc[gt] = __builtin_amdgcn_mfma_f32_16x16x32_bf16(afr[g * 4 + kcl], bf, acc[gt], 0, 0, 0);
      }
    }
    __builtin_amdgcn_s_setprio(0);
    if constexpr (gi < NG - 3) {
      // buffer (g%3) gets overwritten by group g+3: ensure this wave's LDS
      // reads retired (rule #18: pin with sched_barrier), then cross-wave sync.
      asm volatile("s_waitcnt lgkmcnt(0)" ::: "memory");
      __builtin_amdgcn_sched_barrier(0);
      __builtin_amdgcn_s_barrier();
      issueG(g + 3);
    }
  };
  group(IC<0>{});
  if constexpr (NG > 1) group(IC<1>{});
  if constexpr (NG > 2) group(IC<2>{});
  if constexpr (NG > 3) group(IC<3>{});
  if constexpr (NG > 4) group(IC<4>{});
  if constexpr (NG > 5) group(IC<5>{});

  // --- epilogue: lane holds gates i,f,g,o for (rows q*4+r, hidden colh)
#pragma unroll
  for (int r = 0; r < 4; r++) {
    int row = mb * 128 + w * 16 + q * 4 + r;
    size_t cidx = (size_t)row * 1024 + cell * 256 + colh;
    float iv = sigm(acc[0][r] + brg[0]);
    float fv = sigm(acc[1][r] + brg[1]);
    float gv = tanh_f(acc[2][r] + brg[2]);
    float ov = sigm(acc[3][r] + brg[3]);
    float c2 = fv * cp[r] + iv * gv;
    C[cidx] = c2;
    float hv = ov * tanh_f(c2);
    Hw[cidx] = f2bf(hv);
    if (cell0 == 2)  // layer-1 stage: y == output
      out[(size_t)row * (NSTEPS * 512) + step * 512 + (cell - 2) * 256 + colh] = hv;
  }
}

__global__ __launch_bounds__(512, 2) void stage_kernel(
    const unsigned short* __restrict__ Xb, const unsigned short* __restrict__ Hp,
    unsigned short* __restrict__ Hw, float* __restrict__ C,
    const float* __restrict__ bsum, const unsigned short* __restrict__ wpack,
    float* __restrict__ out, int cell0, int step, int kc0) {
  __shared__ unsigned short Blds[3 * 16 * 512];  // 48 KB, triple-buffered groups
  if (kc0 == 16)
    stage_body<16>(Xb, Hp, Hw, C, bsum, wpack, out, cell0, step, Blds);
  else
    stage_body<0>(Xb, Hp, Hw, C, bsum, wpack, out, cell0, step, Blds);
}

extern "C" void kernel_launch(void* const* d_in, const int* in_sizes, int n_in,
                              void* d_out, int out_size, void* d_ws, size_t ws_size,
                              hipStream_t stream) {
  const float* code = (const float*)d_in[0];
  // d_in[1] = x  -- unused by the reference
  const float* Wih0 = (const float*)d_in[2];
  const float* Whh0 = (const float*)d_in[3];
  const float* bih0 = (const float*)d_in[4];
  const float* bhh0 = (const float*)d_in[5];
  const float* Wih1 = (const float*)d_in[6];
  const float* Whh1 = (const float*)d_in[7];
  const float* bih1 = (const float*)d_in[8];
  const float* bhh1 = (const float*)d_in[9];

  // d_ws layout
  unsigned short* wpack = (unsigned short*)d_ws;                        // 6,291,456 B
  float* bsum = (float*)((char*)d_ws + 6291456);                        // 16 KB
  float* C    = (float*)((char*)d_ws + 6291456 + 16384);                // 4 MB
  unsigned short* H0 = (unsigned short*)((char*)d_ws + 6291456 + 16384 + 4194304);  // 2 MB
  unsigned short* H1 = H0 + 1024 * 1024;                                // 2 MB

  float* out = (float*)d_out;

  wpack_kernel<<<1536, 256, 0, stream>>>(Wih0, Whh0, bih0, bhh0,
                                         Wih1, Whh1, bih1, bhh1, wpack, bsum);
  init_kernel<<<4096, 256, 0, stream>>>(code, H1, C);

  for (int t = 0; t < NSTEPS; t++) {
    unsigned short* Hprev = (t & 1) ? H0 : H1;  // slot (t-1)&1
    unsigned short* Hcur  = (t & 1) ? H1 : H0;  // slot t&1
    // stage 0 (layer 0): X = prev y = Hprev cells 2,3; own h = Hprev cells 0,1
    stage_kernel<<<256, 512, 0, stream>>>(Hprev + 512, Hprev, Hcur, C, bsum, wpack,
                                          out, 0, t, (t == 0) ? 16 : 0);
    // stage 1 (layer 1): X = fresh h0 = Hcur cells 0,1; own h = Hprev cells 2,3
    stage_kernel<<<256, 512, 0, stream>>>(Hcur, Hprev, Hcur, C, bsum, wpack,
                                          out, 2, t, 0);
  }
}